// Round 2
// baseline (71.179 us; speedup 1.0000x reference)
//
#include <hip/hip_runtime.h>

#define NN 1024
#define BB 16
#define NTY 3
#define BLOCKS_PER_BATCH (NN / 8)   // 128 blocks of 8 rows per batch

__global__ __launch_bounds__(256) void eam_fused(
    const int* __restrict__ types, const int* __restrict__ n_atoms,
    const float* __restrict__ distances,
    const float* __restrict__ phi_params, const float* __restrict__ rho_params,
    const float* __restrict__ emb_params,
    float* __restrict__ ws_acc, int* __restrict__ ws_cnt,
    float* __restrict__ out)
{
    __shared__ int4   s_types4[NN / 4];
    __shared__ float4 s_tbl[NTY * NTY];
    __shared__ float  s_rowe[8];

    const int tid = threadIdx.x;
    const int b = blockIdx.y;
    const int rowBase = blockIdx.x * 8;

    // stage this batch's types row into LDS (vectorized, 1 int4/thread)
    s_types4[tid] = ((const int4*)(types + b * NN))[tid];

    // 3x3 pair-type table:
    // phi  = p0*exp(-p1*(d-p2))      = (p0*e^{p1 p2})   * 2^{(-p1*log2e)*d}
    // rho² = (r0*exp(-r1*(d-r2)))²   = (r0*e^{r1 r2})²  * 2^{(-2 r1*log2e)*d}
    if (tid < NTY * NTY) {
        const int ti = tid / NTY, tj = tid % NTY;
        const int lo = min(ti, tj), hi = max(ti, tj);
        const int pt = lo * (2 * NTY - lo + 1) / 2 + (hi - lo);
        const float p0 = phi_params[pt * 3 + 0];
        const float p1 = phi_params[pt * 3 + 1];
        const float p2 = phi_params[pt * 3 + 2];
        const float r0 = rho_params[pt * 3 + 0];
        const float r1 = rho_params[pt * 3 + 1];
        const float r2 = rho_params[pt * 3 + 2];
        const float LOG2E = 1.44269504088896f;
        const float ra = r0 * __expf(r1 * r2);
        s_tbl[tid] = make_float4(p0 * __expf(p1 * p2), -p1 * LOG2E,
                                 ra * ra, -2.0f * r1 * LOG2E);
    }
    __syncthreads();

    const int lane = tid & 63;
    const int wave = tid >> 6;
    const int na = n_atoms[b];
    const int npass = (na + 255) >> 8;          // only columns j < na matter
    const int* s_types = (const int*)s_types4;

#pragma unroll
    for (int rr = 0; rr < 2; ++rr) {
        const int i = rowBase + wave * 2 + rr;
        float rowE = 0.f;
        if (i < na) {
            const int ti = s_types[i];
            const float4* drow =
                (const float4*)(distances + ((size_t)(b * NN + i)) * NN);
            float sph = 0.f, srh = 0.f;

            // 1-deep software pipeline over dynamic pass count (2..4)
            float4 d4 = drow[lane];
            for (int pass = 0; pass < npass; ++pass) {
                const int c4 = pass * 64 + lane;
                const float4 cur = d4;
                if (pass + 1 < npass) d4 = drow[c4 + 64];
                const int4 tj4 = s_types4[c4];
                const int jb = c4 * 4;

#define EAM_EL(E, DD, TT)                                                     \
                {                                                             \
                    const float4 prm = s_tbl[ti * NTY + (TT)];                \
                    float phi  = prm.x * __builtin_amdgcn_exp2f(prm.y * (DD));\
                    float rho2 = prm.z * __builtin_amdgcn_exp2f(prm.w * (DD));\
                    const int j = jb + (E);                                   \
                    if (j >= na || j == i) { phi = 0.f; rho2 = 0.f; }         \
                    sph += phi;                                               \
                    srh += rho2;                                              \
                }
                EAM_EL(0, cur.x, tj4.x)
                EAM_EL(1, cur.y, tj4.y)
                EAM_EL(2, cur.z, tj4.z)
                EAM_EL(3, cur.w, tj4.w)
#undef EAM_EL
            }
#pragma unroll
            for (int o = 32; o > 0; o >>= 1) {
                sph += __shfl_xor(sph, o, 64);
                srh += __shfl_xor(srh, o, 64);
            }
            const float A   = emb_params[ti * 2 + 0];
            const float off = emb_params[ti * 2 + 1];
            rowE = sph + (-A * sqrtf(fmaxf(srh, 1e-30f)) + off);
        }
        if (lane == 0) s_rowe[wave * 2 + rr] = rowE;
    }
    __syncthreads();

    if (tid == 0) {
        float s = 0.f;
#pragma unroll
        for (int k = 0; k < 8; ++k) s += s_rowe[k];
        atomicAdd(&ws_acc[b], s);
        __threadfence();
        const int old = atomicAdd(&ws_cnt[b], 1);
        if (old == BLOCKS_PER_BATCH - 1) {
            // all blocks of this batch have contributed (device-scope RMW read)
            const float tot = atomicAdd(&ws_acc[b], 0.0f);
            out[b] = tot / (float)na;
        }
    }
}

extern "C" void kernel_launch(void* const* d_in, const int* in_sizes, int n_in,
                              void* d_out, int out_size, void* d_ws, size_t ws_size,
                              hipStream_t stream) {
    const int*   types      = (const int*)d_in[0];
    const int*   n_atoms    = (const int*)d_in[1];
    const float* distances  = (const float*)d_in[2];
    // d_in[3] = pair_types: recomputed on the fly, not read (saves 64 MB)
    const float* phi_params = (const float*)d_in[4];
    const float* rho_params = (const float*)d_in[5];
    const float* emb_params = (const float*)d_in[6];

    float* ws_acc = (float*)d_ws;          // 16 floats
    int*   ws_cnt = (int*)((char*)d_ws + BB * sizeof(float));  // 16 ints

    // deterministic init of accumulators + completion counters (128 B)
    hipMemsetAsync(d_ws, 0, BB * (sizeof(float) + sizeof(int)), stream);

    eam_fused<<<dim3(BLOCKS_PER_BATCH, BB), 256, 0, stream>>>(
        types, n_atoms, distances, phi_params, rho_params, emb_params,
        ws_acc, ws_cnt, (float*)d_out);
}

// Round 3
// 19.960 us; speedup vs baseline: 3.5661x; 3.5661x over previous
//
#include <hip/hip_runtime.h>

#define NN 1024
#define BB 16
#define NTY 3

// kernel 1: one block = 8 strided rows of one batch (balance), wave = 2 rows.
__global__ __launch_bounds__(256) void eam_rows(
    const int* __restrict__ types, const int* __restrict__ n_atoms,
    const float* __restrict__ distances,
    const float* __restrict__ phi_params, const float* __restrict__ rho_params,
    const float* __restrict__ emb_params, float* __restrict__ blk_part)
{
    __shared__ int4   s_types4[NN / 4];
    __shared__ float4 s_tbl[NTY * NTY];
    __shared__ float  s_rowe[8];

    const int tid = threadIdx.x;
    const int b  = blockIdx.y;
    const int bx = blockIdx.x;              // 0..127

    s_types4[tid] = ((const int4*)(types + b * NN))[tid];

    // phi  = p0*exp(-p1*(d-p2))    = (p0*e^{p1 p2})  * 2^{(-p1*log2e)*d}
    // rho² = (r0*exp(-r1*(d-r2)))² = (r0*e^{r1 r2})² * 2^{(-2 r1*log2e)*d}
    if (tid < NTY * NTY) {
        const int ti = tid / NTY, tj = tid % NTY;
        const int lo = min(ti, tj), hi = max(ti, tj);
        const int pt = lo * (2 * NTY - lo + 1) / 2 + (hi - lo);
        const float p0 = phi_params[pt * 3 + 0];
        const float p1 = phi_params[pt * 3 + 1];
        const float p2 = phi_params[pt * 3 + 2];
        const float r0 = rho_params[pt * 3 + 0];
        const float r1 = rho_params[pt * 3 + 1];
        const float r2 = rho_params[pt * 3 + 2];
        const float LOG2E = 1.44269504088896f;
        const float ra = r0 * __expf(r1 * r2);
        s_tbl[tid] = make_float4(p0 * __expf(p1 * p2), -p1 * LOG2E,
                                 ra * ra, -2.0f * r1 * LOG2E);
    }
    __syncthreads();

    const int lane = tid & 63;
    const int wave = tid >> 6;
    const int na = n_atoms[b];
    const bool p2 = na > 512;   // pass 2 covers cols [512,768)
    const bool p3 = na > 768;   // pass 3 covers cols [768,1024)
    const int* s_types = (const int*)s_types4;

#pragma unroll
    for (int rr = 0; rr < 2; ++rr) {
        const int i = bx + (wave * 2 + rr) * 128;   // strided rows: balanced
        float rowE = 0.f;
        if (i < na) {
            const int ti = s_types[i];
            const float4* drow =
                (const float4*)(distances + ((size_t)(b * NN + i)) * NN);
            // issue all row loads up front (MLP 2..4), uniform guards
            float4 v0 = drow[lane];
            float4 v1 = drow[64 + lane];
            float4 v2 = make_float4(0.f, 0.f, 0.f, 0.f);
            float4 v3 = make_float4(0.f, 0.f, 0.f, 0.f);
            if (p2) v2 = drow[128 + lane];
            if (p3) v3 = drow[192 + lane];

            float sph = 0.f, srh = 0.f;

#define EAM_EL(E, DD, TT, JB)                                                 \
            {                                                                 \
                const float4 prm = s_tbl[ti * NTY + (TT)];                    \
                float phi  = prm.x * __builtin_amdgcn_exp2f(prm.y * (DD));    \
                float rho2 = prm.z * __builtin_amdgcn_exp2f(prm.w * (DD));    \
                const int j = (JB) + (E);                                     \
                if (j >= na || j == i) { phi = 0.f; rho2 = 0.f; }             \
                sph += phi;                                                   \
                srh += rho2;                                                  \
            }
#define EAM_PASS(P, V)                                                        \
            {                                                                 \
                const int c4 = (P) * 64 + lane;                               \
                const int4 tj4 = s_types4[c4];                                \
                const int jb = c4 * 4;                                        \
                EAM_EL(0, (V).x, tj4.x, jb)                                   \
                EAM_EL(1, (V).y, tj4.y, jb)                                   \
                EAM_EL(2, (V).z, tj4.z, jb)                                   \
                EAM_EL(3, (V).w, tj4.w, jb)                                   \
            }
            EAM_PASS(0, v0)
            EAM_PASS(1, v1)
            if (p2) EAM_PASS(2, v2)
            if (p3) EAM_PASS(3, v3)
#undef EAM_PASS
#undef EAM_EL

#pragma unroll
            for (int o = 32; o > 0; o >>= 1) {
                sph += __shfl_xor(sph, o, 64);
                srh += __shfl_xor(srh, o, 64);
            }
            const float A   = emb_params[ti * 2 + 0];
            const float off = emb_params[ti * 2 + 1];
            rowE = sph + (-A * sqrtf(fmaxf(srh, 1e-30f)) + off);
        }
        if (lane == 0) s_rowe[wave * 2 + rr] = rowE;
    }
    __syncthreads();

    if (tid == 0) {
        float s = 0.f;
#pragma unroll
        for (int k = 0; k < 8; ++k) s += s_rowe[k];
        blk_part[b * 128 + bx] = s;   // no atomics, no fences
    }
}

// kernel 2: 16 blocks x 64 lanes; reduce 128 partials per batch, divide.
__global__ __launch_bounds__(64) void eam_reduce(
    const float* __restrict__ blk_part, const int* __restrict__ n_atoms,
    float* __restrict__ out)
{
    const int b = blockIdx.x;
    const int lane = threadIdx.x;
    float s = blk_part[b * 128 + lane] + blk_part[b * 128 + 64 + lane];
#pragma unroll
    for (int o = 32; o > 0; o >>= 1) s += __shfl_xor(s, o, 64);
    if (lane == 0) out[b] = s / (float)n_atoms[b];
}

extern "C" void kernel_launch(void* const* d_in, const int* in_sizes, int n_in,
                              void* d_out, int out_size, void* d_ws, size_t ws_size,
                              hipStream_t stream) {
    const int*   types      = (const int*)d_in[0];
    const int*   n_atoms    = (const int*)d_in[1];
    const float* distances  = (const float*)d_in[2];
    // d_in[3] = pair_types: recomputed on the fly, not read (saves 64 MB)
    const float* phi_params = (const float*)d_in[4];
    const float* rho_params = (const float*)d_in[5];
    const float* emb_params = (const float*)d_in[6];

    float* blk_part = (float*)d_ws;   // 16*128 floats = 8 KB

    eam_rows<<<dim3(128, BB), 256, 0, stream>>>(
        types, n_atoms, distances, phi_params, rho_params, emb_params, blk_part);
    eam_reduce<<<BB, 64, 0, stream>>>(blk_part, n_atoms, (float*)d_out);
}